// Round 2
// baseline (1028.393 us; speedup 1.0000x reference)
//
#include <hip/hip_runtime.h>

// Sinkhorn-Knopp, factored: s_ij = a_ij * u_i * v_j; only u,v evolve.
// R4: R3's coalescing landed (FETCH 223->186MB) but dur only 770->710us.
// Counters isolate the real bottleneck: symmetric excess HBM traffic
// (FETCH +111MB, WRITE +101MB over demand) == scratch spill of ~210
// u32/thread -- the whole R0..R11 matrix. VGPR_Count stayed 128: the
// waves_per_eu occupancy hint did NOT raise the allocator's budget.
// Fixes this round:
//  (1) amdgpu_num_vgpr(256): force the full 2-waves/SIMD register budget
//      (per-SIMD pool 512 regs/lane; block is 8 waves = 2/SIMD; LDS already
//      limits to 1 block/CU so occupancy is unchanged).
//  (2) Col pass split into two 16-accumulator half-passes (half A =
//      R[0..7]/quads 0-1 -> cols 0..15, half B = R[8..15]/quads 2-3 ->
//      cols 16..31; 4-level tree + shfl_xor(16) fold + lane select).
//      Peak live drops ~235 -> ~215 so 256 fits with margin.
#define SEPS 1e-10f

typedef unsigned int uu;
typedef uu v16u __attribute__((ext_vector_type(16)));

#define RPTK12(F) F(0) F(1) F(2) F(3) F(4) F(5) F(6) F(7) F(8) F(9) F(10) F(11)

__device__ __forceinline__ uu bfpack2(float f0, float f1) {
    uu u0 = __float_as_uint(f0 + SEPS);
    uu u1 = __float_as_uint(f1 + SEPS);
    u0 += 0x7FFFu + ((u0 >> 16) & 1u);   // RNE to bf16
    u1 += 0x7FFFu + ((u1 >> 16) & 1u);
    return (u0 >> 16) | (u1 & 0xFFFF0000u);  // low16 = even col, high16 = odd col
}

__global__
__attribute__((amdgpu_flat_work_group_size(512, 512)))
__attribute__((amdgpu_waves_per_eu(2, 2)))
__attribute__((amdgpu_num_vgpr(256)))
void sinkhorn_kernel(const float* __restrict__ s, const int* __restrict__ nrows,
                     const int* __restrict__ ncols, float* __restrict__ out)
{
    // 4 chunks of [32 rows][256 u32] bf16-pairs, quad(16B)-swizzled: 128 KB
    __shared__ __align__(16) uu    spill[4 * 8192];
    __shared__ __align__(16) float red[8][516];   // iter partials; reused as 16KB store staging
    __shared__ float sh_u[512];
    __shared__ float sh_v[512];

    const int b   = blockIdx.x;
    const int tid = threadIdx.x;
    const int tr  = tid & 31;
    const int tc  = tid >> 5;
    const int c0  = tc << 5;
    const int wv  = tid >> 6;
    const int nr  = nrows[b];
    const int nc  = ncols[b];
    const bool cact = (c0 < nc);

    sh_u[tid] = 1.0f;

#define DECLR(k) v16u R##k;
    RPTK12(DECLR)

    const float4* sb4 = (const float4*)(s   + ((size_t)b << 18));
    float4*       ob4 = (float4*)      (out + ((size_t)b << 18));

    // ---- coalesced chunk stage: rows 32k..32k+31 -> dst [32][256] u32, swizzled.
    // f = float4 index in chunk; consecutive lanes -> consecutive 16B (coalesced).
    // Masks (row>=nr, col>=nc -> 0) applied here, so readers are pure copies.
#define STAGE_CHUNK(k, dst) { \
    _Pragma("unroll") \
    for (int i__ = 0; i__ < 8; ++i__) { \
        const int f__  = i__ * 512 + tid; \
        const int rr__ = f__ >> 7; \
        const int p__  = f__ & 127; \
        const int cc__ = p__ << 2; \
        const int r__  = 32*(k) + rr__; \
        float4 w__ = make_float4(0.f, 0.f, 0.f, 0.f); \
        if (r__ < nr && cc__ < nc) w__ = sb4[(k)*4096 + f__]; \
        const int rem__ = nc - cc__; \
        const uu mA__ = (rem__ >= 2) ? 0xFFFFFFFFu : ((rem__ == 1) ? 0x0000FFFFu : 0u); \
        const uu mB__ = (rem__ >= 4) ? 0xFFFFFFFFu : ((rem__ == 3) ? 0x0000FFFFu : 0u); \
        const uu rm__ = (r__ < nr) ? 0xFFFFFFFFu : 0u; \
        uint2 pr__; \
        pr__.x = bfpack2(w__.x, w__.y) & mA__ & rm__; \
        pr__.y = bfpack2(w__.z, w__.w) & mB__ & rm__; \
        *(uint2*)((dst) + rr__*256 + ((((p__ >> 1) ^ (rr__ & 7)) << 2) | ((p__ & 1) << 1))) = pr__; \
    } }

    // ---- distribute staged chunk (at spill[0]) into this thread's R##k
#define DIST_CHUNK(k) { \
    const uu* rb__ = spill + tr*256; \
    const int x__  = tr & 7; \
    uint4 t0__ = *(const uint4*)(rb__ + ((((tc<<2)+0) ^ x__) << 2)); \
    uint4 t1__ = *(const uint4*)(rb__ + ((((tc<<2)+1) ^ x__) << 2)); \
    uint4 t2__ = *(const uint4*)(rb__ + ((((tc<<2)+2) ^ x__) << 2)); \
    uint4 t3__ = *(const uint4*)(rb__ + ((((tc<<2)+3) ^ x__) << 2)); \
    R##k[0]=t0__.x;  R##k[1]=t0__.y;  R##k[2]=t0__.z;  R##k[3]=t0__.w; \
    R##k[4]=t1__.x;  R##k[5]=t1__.y;  R##k[6]=t1__.z;  R##k[7]=t1__.w; \
    R##k[8]=t2__.x;  R##k[9]=t2__.y;  R##k[10]=t2__.z; R##k[11]=t2__.w; \
    R##k[12]=t3__.x; R##k[13]=t3__.y; R##k[14]=t3__.z; R##k[15]=t3__.w; }

    // load order: 15,14,13 direct-scatter; 0..11 staged in chunk-12 region; 12 last
    if (480 < nr) STAGE_CHUNK(15, spill + 3*8192)
    if (448 < nr) STAGE_CHUNK(14, spill + 2*8192)
    if (416 < nr) STAGE_CHUNK(13, spill + 1*8192)
#define LOADK(k) if (32*(k) < nr) { \
    STAGE_CHUNK(k, spill) \
    __syncthreads(); \
    DIST_CHUNK(k) \
    __syncthreads(); }
    RPTK12(LOADK)
    if (384 < nr) STAGE_CHUNK(12, spill)
    __syncthreads();   // spill + sh_u visible

    // quad q of thread (tr,tc) in spill chunk k (k=12..15)
#define SPQ(k, q) ((const uint4*)(spill + ((k)-12)*8192 + tr*256 + ((((tc<<2)+(q)) ^ (tr & 7)) << 2)))

#define UFW(w, uk, A, B) { const uu w__ = (w); \
    A += __uint_as_float(w__ << 16) * (uk); \
    B += __uint_as_float(w__ & 0xFFFF0000u) * (uk); }

    // ---- col pass half A: R##k[0..7] -> cols 0..15 of this tc group
#define COLKA(k) if (32*(k) < nr && cact) { \
    const float uk__ = sh_u[tr + 32*(k)]; \
    UFW(R##k[0], uk__, ca0,  ca1)  UFW(R##k[1], uk__, ca2,  ca3) \
    UFW(R##k[2], uk__, ca4,  ca5)  UFW(R##k[3], uk__, ca6,  ca7) \
    UFW(R##k[4], uk__, ca8,  ca9)  UFW(R##k[5], uk__, ca10, ca11) \
    UFW(R##k[6], uk__, ca12, ca13) UFW(R##k[7], uk__, ca14, ca15) }

    // ---- col pass half B: R##k[8..15] -> cols 16..31 of this tc group
#define COLKB(k) if (32*(k) < nr && cact) { \
    const float uk__ = sh_u[tr + 32*(k)]; \
    UFW(R##k[8],  uk__, cb0,  cb1)  UFW(R##k[9],  uk__, cb2,  cb3) \
    UFW(R##k[10], uk__, cb4,  cb5)  UFW(R##k[11], uk__, cb6,  cb7) \
    UFW(R##k[12], uk__, cb8,  cb9)  UFW(R##k[13], uk__, cb10, cb11) \
    UFW(R##k[14], uk__, cb12, cb13) UFW(R##k[15], uk__, cb14, cb15) }

#define COLLDSQ(k, q, A0,A1,A2,A3,A4,A5,A6,A7) { \
    uint4 t__ = *SPQ(k,q); \
    UFW(t__.x, uk__, A0, A1) UFW(t__.y, uk__, A2, A3) \
    UFW(t__.z, uk__, A4, A5) UFW(t__.w, uk__, A6, A7) }

#define COLLDSA(k) if (32*(k) < nr && cact) { \
    const float uk__ = sh_u[tr + 32*(k)]; \
    COLLDSQ(k,0, ca0,ca1,ca2,ca3,ca4,ca5,ca6,ca7) \
    COLLDSQ(k,1, ca8,ca9,ca10,ca11,ca12,ca13,ca14,ca15) }

#define COLLDSB(k) if (32*(k) < nr && cact) { \
    const float uk__ = sh_u[tr + 32*(k)]; \
    COLLDSQ(k,2, cb0,cb1,cb2,cb3,cb4,cb5,cb6,cb7) \
    COLLDSQ(k,3, cb8,cb9,cb10,cb11,cb12,cb13,cb14,cb15) }

    // shuffle-tree stage: keep cols matching own lane bit, add partner's
#define TST(m, OUT, A0, A1) float OUT; { \
    const float t0__ = __shfl_xor(A0, m); \
    const float t1__ = __shfl_xor(A1, m); \
    OUT = (tid & (m)) ? ((A1) + t1__) : ((A0) + t0__); }

#define RWH(w, VA, VB) { const uu w__ = (w); \
    acc__ += __uint_as_float(w__ << 16) * (VA); \
    acc__ += __uint_as_float(w__ & 0xFFFF0000u) * (VB); }

#define ROWBODY(P) \
    RWH(P[0],  vz0.x, vz0.y) RWH(P[1],  vz0.z, vz0.w) \
    RWH(P[2],  vz1.x, vz1.y) RWH(P[3],  vz1.z, vz1.w) \
    RWH(P[4],  vz2.x, vz2.y) RWH(P[5],  vz2.z, vz2.w) \
    RWH(P[6],  vz3.x, vz3.y) RWH(P[7],  vz3.z, vz3.w) \
    RWH(P[8],  vz4.x, vz4.y) RWH(P[9],  vz4.z, vz4.w) \
    RWH(P[10], vz5.x, vz5.y) RWH(P[11], vz5.z, vz5.w) \
    RWH(P[12], vz6.x, vz6.y) RWH(P[13], vz6.z, vz6.w) \
    RWH(P[14], vz7.x, vz7.y) RWH(P[15], vz7.z, vz7.w)

#define ROWK(k) { float acc__ = 0.0f; \
    if (32*(k) < nr && cact) { ROWBODY(R##k) } \
    acc__ += __shfl_xor(acc__, 32); \
    if ((tid & 32) == 0) red[wv][tr + 32*(k)] = acc__; }

#define ROWLDSQ(k,q, VA0,VB0,VA1,VB1,VA2,VB2,VA3,VB3) { \
    uint4 t__ = *SPQ(k,q); \
    RWH(t__.x, VA0, VB0) RWH(t__.y, VA1, VB1) \
    RWH(t__.z, VA2, VB2) RWH(t__.w, VA3, VB3) }

#define ROWLDSK(k) { float acc__ = 0.0f; \
    if (32*(k) < nr && cact) { \
      ROWLDSQ(k,0, vz0.x,vz0.y, vz0.z,vz0.w, vz1.x,vz1.y, vz1.z,vz1.w) \
      ROWLDSQ(k,1, vz2.x,vz2.y, vz2.z,vz2.w, vz3.x,vz3.y, vz3.z,vz3.w) \
      ROWLDSQ(k,2, vz4.x,vz4.y, vz4.z,vz4.w, vz5.x,vz5.y, vz5.z,vz5.w) \
      ROWLDSQ(k,3, vz6.x,vz6.y, vz6.z,vz6.w, vz7.x,vz7.y, vz7.z,vz7.w) } \
    acc__ += __shfl_xor(acc__, 32); \
    if ((tid & 32) == 0) red[wv][tr + 32*(k)] = acc__; }

#pragma unroll 1
    for (int it = 0; it < 10; ++it) {
        // ---- col pass: c_j = sum_i a_ij u_i, two halves of 16 accumulators
        float hA, hB;
        {
            float ca0=0.0f,ca1=0.0f,ca2=0.0f,ca3=0.0f,ca4=0.0f,ca5=0.0f,ca6=0.0f,ca7=0.0f,
                  ca8=0.0f,ca9=0.0f,ca10=0.0f,ca11=0.0f,ca12=0.0f,ca13=0.0f,ca14=0.0f,ca15=0.0f;
            RPTK12(COLKA)
            COLLDSA(12) COLLDSA(13) COLLDSA(14) COLLDSA(15)
            TST(1, d0, ca0,  ca1)  TST(1, d1, ca2,  ca3)  TST(1, d2, ca4,  ca5)  TST(1, d3, ca6,  ca7)
            TST(1, d4, ca8,  ca9)  TST(1, d5, ca10, ca11) TST(1, d6, ca12, ca13) TST(1, d7, ca14, ca15)
            TST(2, e0, d0, d1) TST(2, e1, d2, d3) TST(2, e2, d4, d5) TST(2, e3, d6, d7)
            TST(4, f0, e0, e1) TST(4, f1, e2, e3)
            TST(8, g0, f0, f1)
            hA = g0 + __shfl_xor(g0, 16);   // fold the tr-bit4 halves (same col)
        }
        {
            float cb0=0.0f,cb1=0.0f,cb2=0.0f,cb3=0.0f,cb4=0.0f,cb5=0.0f,cb6=0.0f,cb7=0.0f,
                  cb8=0.0f,cb9=0.0f,cb10=0.0f,cb11=0.0f,cb12=0.0f,cb13=0.0f,cb14=0.0f,cb15=0.0f;
            RPTK12(COLKB)
            COLLDSB(12) COLLDSB(13) COLLDSB(14) COLLDSB(15)
            TST(1, d0, cb0,  cb1)  TST(1, d1, cb2,  cb3)  TST(1, d2, cb4,  cb5)  TST(1, d3, cb6,  cb7)
            TST(1, d4, cb8,  cb9)  TST(1, d5, cb10, cb11) TST(1, d6, cb12, cb13) TST(1, d7, cb14, cb15)
            TST(2, e0, d0, d1) TST(2, e1, d2, d3) TST(2, e2, d4, d5) TST(2, e3, d6, d7)
            TST(4, f0, e0, e1) TST(4, f1, e2, e3)
            TST(8, g0, f0, f1)
            hB = g0 + __shfl_xor(g0, 16);
        }
        // lane tr<16 owns col c0+(tr&15) from half A; tr>=16 owns c0+16+(tr&15) from B
        const float h0 = (tr & 16) ? hB : hA;
        sh_v[tid] = (h0 > 0.0f) ? 1.0f / h0 : 1.0f;
        __syncthreads();

        // ---- row pass: r_i = sum_j a_ij v_j
        float4 vz0 = *(const float4*)&sh_v[c0 +  0];
        float4 vz1 = *(const float4*)&sh_v[c0 +  4];
        float4 vz2 = *(const float4*)&sh_v[c0 +  8];
        float4 vz3 = *(const float4*)&sh_v[c0 + 12];
        float4 vz4 = *(const float4*)&sh_v[c0 + 16];
        float4 vz5 = *(const float4*)&sh_v[c0 + 20];
        float4 vz6 = *(const float4*)&sh_v[c0 + 24];
        float4 vz7 = *(const float4*)&sh_v[c0 + 28];
        RPTK12(ROWK)
        ROWLDSK(12) ROWLDSK(13) ROWLDSK(14) ROWLDSK(15)
        __syncthreads();
        {   // u_i = 1 / sum of 8 wave-partials; row id == tid
            float ss = red[0][tid] + red[1][tid] + red[2][tid] + red[3][tid]
                     + red[4][tid] + red[5][tid] + red[6][tid] + red[7][tid];
            sh_u[tid] = (ss > 0.0f) ? 1.0f / ss : 1.0f;
        }
        __syncthreads();
    }

    // ---- epilogue: out = a * u_i * v_j, all stores wave-coalesced via LDS staging
    float4 vz0 = *(const float4*)&sh_v[c0 +  0];
    float4 vz1 = *(const float4*)&sh_v[c0 +  4];
    float4 vz2 = *(const float4*)&sh_v[c0 +  8];
    float4 vz3 = *(const float4*)&sh_v[c0 + 12];
    float4 vz4 = *(const float4*)&sh_v[c0 + 16];
    float4 vz5 = *(const float4*)&sh_v[c0 + 20];
    float4 vz6 = *(const float4*)&sh_v[c0 + 24];
    float4 vz7 = *(const float4*)&sh_v[c0 + 28];

#define EPW(w, UK, VA, VB, OX, OY) { const uu w__ = (w); \
    OX = __uint_as_float(w__ << 16) * (UK) * (VA); \
    OY = __uint_as_float(w__ & 0xFFFF0000u) * (UK) * (VB); }

    float* const redf = (float*)red;      // [8][512] f32 staging, quad-swizzled
    float* const stF  = (float*)spill;    // [32][512] f32 staging (chunks 12+13 region)

    // spill rows k=12..15 first (frees the spill region), via red[] in 8-row subchunks
#define STSPILLK(k) \
    if (32*(k) >= nr) { \
        const float4 z__ = make_float4(0.f,0.f,0.f,0.f); \
        _Pragma("unroll") \
        for (int i__ = 0; i__ < 8; ++i__) { \
            const int f__ = i__*512 + tid; \
            ob4[(size_t)(32*(k) + (f__ >> 7))*128 + (f__ & 127)] = z__; \
        } \
    } else { \
        for (int rg__ = 0; rg__ < 4; ++rg__) { \
            if ((tr >> 3) == rg__) { \
                const float uk__ = sh_u[tr + 32*(k)]; \
                float* sr__ = redf + (tr & 7)*512; \
                const int x__ = tr & 7; \
                uint4 q0__ = *SPQ(k,0); uint4 q1__ = *SPQ(k,1); \
                uint4 q2__ = *SPQ(k,2); uint4 q3__ = *SPQ(k,3); \
                float4 o__; \
                EPW(q0__.x, uk__, vz0.x, vz0.y, o__.x, o__.y) EPW(q0__.y, uk__, vz0.z, vz0.w, o__.z, o__.w) \
                *(float4*)&sr__[((((tc<<3)+0) ^ x__) << 2)] = o__; \
                EPW(q0__.z, uk__, vz1.x, vz1.y, o__.x, o__.y) EPW(q0__.w, uk__, vz1.z, vz1.w, o__.z, o__.w) \
                *(float4*)&sr__[((((tc<<3)+1) ^ x__) << 2)] = o__; \
                EPW(q1__.x, uk__, vz2.x, vz2.y, o__.x, o__.y) EPW(q1__.y, uk__, vz2.z, vz2.w, o__.z, o__.w) \
                *(float4*)&sr__[((((tc<<3)+2) ^ x__) << 2)] = o__; \
                EPW(q1__.z, uk__, vz3.x, vz3.y, o__.x, o__.y) EPW(q1__.w, uk__, vz3.z, vz3.w, o__.z, o__.w) \
                *(float4*)&sr__[((((tc<<3)+3) ^ x__) << 2)] = o__; \
                EPW(q2__.x, uk__, vz4.x, vz4.y, o__.x, o__.y) EPW(q2__.y, uk__, vz4.z, vz4.w, o__.z, o__.w) \
                *(float4*)&sr__[((((tc<<3)+4) ^ x__) << 2)] = o__; \
                EPW(q2__.z, uk__, vz5.x, vz5.y, o__.x, o__.y) EPW(q2__.w, uk__, vz5.z, vz5.w, o__.z, o__.w) \
                *(float4*)&sr__[((((tc<<3)+5) ^ x__) << 2)] = o__; \
                EPW(q3__.x, uk__, vz6.x, vz6.y, o__.x, o__.y) EPW(q3__.y, uk__, vz6.z, vz6.w, o__.z, o__.w) \
                *(float4*)&sr__[((((tc<<3)+6) ^ x__) << 2)] = o__; \
                EPW(q3__.z, uk__, vz7.x, vz7.y, o__.x, o__.y) EPW(q3__.w, uk__, vz7.z, vz7.w, o__.z, o__.w) \
                *(float4*)&sr__[((((tc<<3)+7) ^ x__) << 2)] = o__; \
            } \
            __syncthreads(); \
            _Pragma("unroll") \
            for (int i__ = 0; i__ < 2; ++i__) { \
                const int f__ = i__*512 + tid; \
                const int r8__ = f__ >> 7; const int bb__ = f__ & 127; \
                float4 o__ = *(const float4*)&redf[r8__*512 + ((bb__ ^ r8__) << 2)]; \
                ob4[(size_t)(32*(k) + (rg__<<3) + r8__)*128 + bb__] = o__; \
            } \
            __syncthreads(); \
        } }
    STSPILLK(12); STSPILLK(13); STSPILLK(14); STSPILLK(15);

    // register rows k=0..11 via the freed 64KB spill region
#define STREGK(k) { \
    if (32*(k) < nr) { \
        const float uk__ = sh_u[tr + 32*(k)]; \
        float* sr__ = stF + tr*512; \
        const int x__ = tr & 7; \
        float4 o__; \
        EPW(R##k[0],  uk__, vz0.x, vz0.y, o__.x, o__.y) EPW(R##k[1],  uk__, vz0.z, vz0.w, o__.z, o__.w) \
        *(float4*)&sr__[((((tc<<3)+0) ^ x__) << 2)] = o__; \
        EPW(R##k[2],  uk__, vz1.x, vz1.y, o__.x, o__.y) EPW(R##k[3],  uk__, vz1.z, vz1.w, o__.z, o__.w) \
        *(float4*)&sr__[((((tc<<3)+1) ^ x__) << 2)] = o__; \
        EPW(R##k[4],  uk__, vz2.x, vz2.y, o__.x, o__.y) EPW(R##k[5],  uk__, vz2.z, vz2.w, o__.z, o__.w) \
        *(float4*)&sr__[((((tc<<3)+2) ^ x__) << 2)] = o__; \
        EPW(R##k[6],  uk__, vz3.x, vz3.y, o__.x, o__.y) EPW(R##k[7],  uk__, vz3.z, vz3.w, o__.z, o__.w) \
        *(float4*)&sr__[((((tc<<3)+3) ^ x__) << 2)] = o__; \
        EPW(R##k[8],  uk__, vz4.x, vz4.y, o__.x, o__.y) EPW(R##k[9],  uk__, vz4.z, vz4.w, o__.z, o__.w) \
        *(float4*)&sr__[((((tc<<3)+4) ^ x__) << 2)] = o__; \
        EPW(R##k[10], uk__, vz5.x, vz5.y, o__.x, o__.y) EPW(R##k[11], uk__, vz5.z, vz5.w, o__.z, o__.w) \
        *(float4*)&sr__[((((tc<<3)+5) ^ x__) << 2)] = o__; \
        EPW(R##k[12], uk__, vz6.x, vz6.y, o__.x, o__.y) EPW(R##k[13], uk__, vz6.z, vz6.w, o__.z, o__.w) \
        *(float4*)&sr__[((((tc<<3)+6) ^ x__) << 2)] = o__; \
        EPW(R##k[14], uk__, vz7.x, vz7.y, o__.x, o__.y) EPW(R##k[15], uk__, vz7.z, vz7.w, o__.z, o__.w) \
        *(float4*)&sr__[((((tc<<3)+7) ^ x__) << 2)] = o__; \
        __syncthreads(); \
        _Pragma("unroll") \
        for (int i__ = 0; i__ < 8; ++i__) { \
            const int f__ = i__*512 + tid; \
            const int rr__ = f__ >> 7; const int bb__ = f__ & 127; \
            float4 o2__ = *(const float4*)&stF[rr__*512 + ((bb__ ^ (rr__ & 7)) << 2)]; \
            ob4[(size_t)(32*(k) + rr__)*128 + bb__] = o2__; \
        } \
        __syncthreads(); \
    } else { \
        const float4 z__ = make_float4(0.f,0.f,0.f,0.f); \
        _Pragma("unroll") \
        for (int i__ = 0; i__ < 8; ++i__) { \
            const int f__ = i__*512 + tid; \
            ob4[(size_t)(32*(k) + (f__ >> 7))*128 + (f__ & 127)] = z__; \
        } \
    } }
    RPTK12(STREGK)
}

extern "C" void kernel_launch(void* const* d_in, const int* in_sizes, int n_in,
                              void* d_out, int out_size, void* d_ws, size_t ws_size,
                              hipStream_t stream) {
    const float* s     = (const float*)d_in[0];
    const int*   nrows = (const int*)d_in[1];
    const int*   ncols = (const int*)d_in[2];
    float*       out   = (float*)d_out;
    const int B = in_sizes[1];   // 256 batches, one 512-thread block (one CU) each
    sinkhorn_kernel<<<dim3(B), dim3(512), 0, stream>>>(s, nrows, ncols, out);
}

// Round 4
// 857.708 us; speedup vs baseline: 1.1990x; 1.1990x over previous
//
#include <hip/hip_runtime.h>

// Sinkhorn-Knopp, factored: s_ij = a_ij * u_i * v_j; only u,v evolve.
// R6 redesign: three rounds showed the allocator pins VGPR_Count=128 while
// the register-residency scheme needs ~230 live -> permanent scratch spill
// (FETCH/WRITE +110MB symmetric excess, 97% stall, 742us). AGPR forcing
// (R5) killed the container. New plan: drop on-chip residency entirely.
// The bf16 matrix is 128 MB total == L3-resident. Persist TWO bf16 copies
// per batch inside the (1MB/batch) output buffer:
//   W1 = transposed [256 jpair][512 i]  at out+0      (row pass, epilogue-dead)
//   W0 = row-major  [512 i][256 jpair]  at out+512KB  (col pass + epilogue)
// Each pass streams 512KB/block from L3, lane-consecutive 4B coalesced,
// u/v weights are wave-uniform LDS broadcasts. 1024 thr/block (4 waves/SIMD)
// for latency hiding; VGPR pressure ~tiny; no spill possible.
// Epilogue overwrite ordering: f32 chunk k (rows 32k..32k+31) destroys only
// W0 chunks <= k, and each chunk is read into LDS before its f32 write.
#define SEPS 1e-10f
typedef unsigned int uu;

__device__ __forceinline__ uu bfpack2(float f0, float f1) {
    uu u0 = __float_as_uint(f0 + SEPS);
    uu u1 = __float_as_uint(f1 + SEPS);
    u0 += 0x7FFFu + ((u0 >> 16) & 1u);   // RNE to bf16
    u1 += 0x7FFFu + ((u1 >> 16) & 1u);
    return (u0 >> 16) | (u1 & 0xFFFF0000u);  // low16 = even col, high16 = odd col
}
__device__ __forceinline__ float blo(uu w){ return __uint_as_float(w << 16); }
__device__ __forceinline__ float bhi(uu w){ return __uint_as_float(w & 0xFFFF0000u); }

__global__
__attribute__((amdgpu_flat_work_group_size(1024, 1024)))
void sinkhorn_kernel(const float* __restrict__ s, const int* __restrict__ nrows,
                     const int* __restrict__ ncols, float* __restrict__ out)
{
    __shared__ __align__(16) uu    shmem[9216];   // 36KB: A-transpose tile / B-partials / C-tile
    __shared__ __align__(16) float sh_u[512];
    __shared__ __align__(16) float sh_v[512];

    const int b   = blockIdx.x;
    const int tid = threadIdx.x;
    const int nr  = nrows[b];
    const int nc  = ncols[b];

    float*       ob  = out + ((size_t)b << 18);
    uu*          W1  = (uu*)ob;              // transposed copy [j][i]
    uu*          W0  = (uu*)ob + 131072;     // row-major copy [i][j]
    const float4* sb4 = (const float4*)(s + ((size_t)b << 18));
    float4*       ob4 = (float4*)ob;

    if (tid < 512) sh_u[tid] = 1.0f;

    // ---------------- phase A: read f32, pack+mask bf16, write both copies
    uu* tlE = shmem;            // [32][129] even-pair lane
    uu* tlO = shmem + 4128;     // [32][129] odd-pair lane
    for (int ti = 0; ti < 16; ++ti) {
        const int i0 = ti << 5;
        #pragma unroll
        for (int it = 0; it < 4; ++it) {
            const int f  = it * 1024 + tid;
            const int rr = f >> 7, p = f & 127;
            const int r  = i0 + rr;
            float4 w = sb4[(ti << 12) + f];
            const int rem = nc - 4 * p;
            const uu mA = (rem >= 2) ? 0xFFFFFFFFu : ((rem == 1) ? 0x0000FFFFu : 0u);
            const uu mB = (rem >= 4) ? 0xFFFFFFFFu : ((rem == 3) ? 0x0000FFFFu : 0u);
            const uu rm = (r < nr) ? 0xFFFFFFFFu : 0u;
            const uu px = bfpack2(w.x, w.y) & mA & rm;
            const uu py = bfpack2(w.z, w.w) & mB & rm;
            *(uint2*)(W0 + r * 256 + 2 * p) = make_uint2(px, py);   // coalesced 8B/lane
            tlE[rr * 129 + p] = px;                                  // 2-way bank max (free)
            tlO[rr * 129 + p] = py;
        }
        __syncthreads();
        #pragma unroll
        for (int it = 0; it < 8; ++it) {
            const int g  = it * 1024 + tid;
            const int j  = g >> 5, ii = g & 31;
            const uu* tl = (j & 1) ? tlO : tlE;
            W1[j * 512 + i0 + ii] = tl[ii * 129 + (j >> 1)];        // conflict-free read, 128B runs
        }
        __syncthreads();
    }

    // ---------------- phase B: 10 x (col pass, row pass), streaming from L3
    float* cp = (float*)shmem;   // cpE[4][256] @0, cpO[4][256] @1024, rp[2][512] @2048
    #pragma unroll 1
    for (int itn = 0; itn < 10; ++itn) {
        // col pass: c_j = sum_i a_ij u_i. thread owns jpair (tid&255), quarter of rows.
        {
            const int j = tid & 255, q = tid >> 8;
            const uu* p = W0 + (q << 7) * 256 + j;      // lane-consecutive 4B, stride 1KB
            const float* us = sh_u + (q << 7);          // wave-uniform broadcast
            float ce = 0.f, co = 0.f;
            #pragma unroll 32
            for (int i = 0; i < 128; ++i) {
                const uu w = p[i * 256];
                const float ui = us[i];
                ce += blo(w) * ui; co += bhi(w) * ui;
            }
            cp[q * 256 + j]        = ce;
            cp[1024 + q * 256 + j] = co;
        }
        __syncthreads();
        if (tid < 512) {
            const int j = tid >> 1;
            const int off = (tid & 1) ? 1024 : 0;
            const float sum = cp[off + j] + cp[off + 256 + j] + cp[off + 512 + j] + cp[off + 768 + j];
            sh_v[tid] = (sum > 0.f) ? 1.f / sum : 1.f;
        }
        __syncthreads();
        // row pass: r_i = sum_j a_ij v_j. thread owns row (tid&511), half of jpairs.
        {
            const int i = tid & 511, h = tid >> 9;
            const uu* p = W1 + (h << 7) * 512 + i;      // lane-consecutive 4B, stride 2KB
            const float2* vs = (const float2*)sh_v + (h << 7);  // wave-uniform broadcast
            float r = 0.f;
            #pragma unroll 32
            for (int j = 0; j < 128; ++j) {
                const uu w = p[j * 512];
                const float2 v2 = vs[j];
                r += blo(w) * v2.x + bhi(w) * v2.y;
            }
            cp[2048 + h * 512 + i] = r;
        }
        __syncthreads();
        if (tid < 512) {
            const float sum = cp[2048 + tid] + cp[2560 + tid];
            sh_u[tid] = (sum > 0.f) ? 1.f / sum : 1.f;
        }
        __syncthreads();
    }

    // ---------------- phase C: epilogue out = a*u*v via W0 chunks in LDS
    {
        const int p  = tid & 127;    // float4 index within a row
        const int rs = tid >> 7;     // 0..7
        const float4 vv = make_float4(sh_v[4*p], sh_v[4*p+1], sh_v[4*p+2], sh_v[4*p+3]);
        uint4* t4 = (uint4*)shmem;
        const uint2* t2 = (const uint2*)shmem;
        #pragma unroll 1
        for (int k = 0; k < 16; ++k) {
            const uint4* src = (const uint4*)(W0 + (k << 13));
            t4[tid]        = src[tid];          // read chunk k BEFORE any row>=32k f32 write
            t4[tid + 1024] = src[tid + 1024];
            __syncthreads();
            #pragma unroll
            for (int it = 0; it < 4; ++it) {
                const int rr = (it << 3) + rs;
                const uint2 tw = t2[rr * 128 + p];
                const float uk = sh_u[(k << 5) + rr];   // wave-uniform
                float4 o;
                o.x = blo(tw.x) * uk * vv.x;
                o.y = bhi(tw.x) * uk * vv.y;
                o.z = blo(tw.y) * uk * vv.z;
                o.w = bhi(tw.y) * uk * vv.w;
                ob4[((k << 5) + rr) * 128 + p] = o;     // coalesced 16B/lane
            }
            __syncthreads();   // chunk-k stores visible before chunk k+1 reads/overwrites
        }
    }
}

extern "C" void kernel_launch(void* const* d_in, const int* in_sizes, int n_in,
                              void* d_out, int out_size, void* d_ws, size_t ws_size,
                              hipStream_t stream) {
    const float* s     = (const float*)d_in[0];
    const int*   nrows = (const int*)d_in[1];
    const int*   ncols = (const int*)d_in[2];
    float*       out   = (float*)d_out;
    const int B = in_sizes[1];   // 256 batches, one 1024-thread block each
    sinkhorn_kernel<<<dim3(B), dim3(1024), 0, stream>>>(s, nrows, ncols, out);
}

// Round 5
// 670.875 us; speedup vs baseline: 1.5329x; 1.2785x over previous
//
#include <hip/hip_runtime.h>

// Sinkhorn-Knopp, factored: s_ij = a_ij * u_i * v_j; only u,v evolve.
// R7: R6 (two global bf16 copies, 20 separate passes) hit 562us with
// FETCH=1.5GB at 46% HBM: the 256MB two-copy working set == L3 size, so
// half the 2.56GB of pass reads missed L3. Fixes:
//  (1) FUSED sweep: one wave reads a whole 1KB row (uint4/lane), row-sum
//      via 6-step shfl_xor tree -> u_i in-wave (no LDS/barrier), then
//      immediately accumulates c_j += a_ij*u_i into per-lane register
//      column accumulators. One matrix read = row pass + next col sums.
//      Schedule: 1 col-only + 9 fused + 1 row-only = 10 col + 10 row.
//      Matrix reads: 20 -> 11.
//  (2) SINGLE row-major copy W0 (at out+512KB): resident set 128MB -> L3-
//      resident during sweeps. Epilogue reads W0 directly; overwrite
//      ordering: out chunk m destroys W0 rows 64(m-8)..+63, read by chunks
//      2(m-8),2(m-8)+1 < m -> barrier before each chunk m>=8; chunk 15
//      self-conflict handled by pre-staging its 32KB into LDS.
#define SEPS 1e-10f
typedef unsigned int uu;

__device__ __forceinline__ uu bfpack2(float f0, float f1) {
    uu u0 = __float_as_uint(f0 + SEPS);
    uu u1 = __float_as_uint(f1 + SEPS);
    u0 += 0x7FFFu + ((u0 >> 16) & 1u);   // RNE to bf16
    u1 += 0x7FFFu + ((u1 >> 16) & 1u);
    return (u0 >> 16) | (u1 & 0xFFFF0000u);  // low16 = even col, high16 = odd col
}
__device__ __forceinline__ float blo(uu w){ return __uint_as_float(w << 16); }
__device__ __forceinline__ float bhi(uu w){ return __uint_as_float(w & 0xFFFF0000u); }
__device__ __forceinline__ float grcp(float x){ return (x > 0.f) ? __builtin_amdgcn_rcpf(x) : 1.f; }

__global__
__attribute__((amdgpu_flat_work_group_size(1024, 1024)))
void sinkhorn_kernel(const float* __restrict__ s, const int* __restrict__ nrows,
                     const int* __restrict__ ncols, float* __restrict__ out)
{
    __shared__ __align__(16) float cpart[16][512];   // 32KB col partials; reused as epilogue stage
    __shared__ float sh_u[512];
    __shared__ float sh_v[512];

    const int b   = blockIdx.x;
    const int tid = threadIdx.x;
    const int wv  = tid >> 6;    // wave 0..15
    const int wl  = tid & 63;    // lane
    const int nr  = nrows[b];
    const int nc  = ncols[b];

    float* ob = out + ((size_t)b << 18);
    uu*    W0 = (uu*)ob + 131072;            // [512 rows][256 jpair] bf16-pairs at out+512KB
    const float4* sb4 = (const float4*)(s + ((size_t)b << 18));
    float4* ob4 = (float4*)ob;

    // ---------------- phase A: pack+mask input -> W0 (coalesced, no LDS)
    #pragma unroll 4
    for (int it = 0; it < 64; ++it) {
        const int f = it * 1024 + tid;
        const int r = f >> 7, p = f & 127;
        float4 w = sb4[f];
        const int rem = nc - 4 * p;
        const uu mA = (rem >= 2) ? 0xFFFFFFFFu : ((rem == 1) ? 0x0000FFFFu : 0u);
        const uu mB = (rem >= 4) ? 0xFFFFFFFFu : ((rem == 3) ? 0x0000FFFFu : 0u);
        const uu rm = (r < nr) ? 0xFFFFFFFFu : 0u;
        *(uint2*)(W0 + r * 256 + 2 * p) = make_uint2(bfpack2(w.x, w.y) & mA & rm,
                                                     bfpack2(w.z, w.w) & mB & rm);
    }
    __syncthreads();   // W0 visible block-wide

    const uu* wp = W0 + wl * 4;   // this lane's jpair quad base (cols 8wl..8wl+7)

    // ---------------- initial col-only pass (u = 1)
    {
        float ce0=0,co0=0,ce1=0,co1=0,ce2=0,co2=0,ce3=0,co3=0;
        #pragma unroll 4
        for (int g = 0; g < 32; ++g) {
            const int i = (g << 4) + wv;
            uint4 wq = *(const uint4*)(wp + i * 256);
            ce0 += blo(wq.x); co0 += bhi(wq.x);
            ce1 += blo(wq.y); co1 += bhi(wq.y);
            ce2 += blo(wq.z); co2 += bhi(wq.z);
            ce3 += blo(wq.w); co3 += bhi(wq.w);
        }
        float* cw = &cpart[wv][wl * 8];
        cw[0]=ce0; cw[1]=co0; cw[2]=ce1; cw[3]=co1;
        cw[4]=ce2; cw[5]=co2; cw[6]=ce3; cw[7]=co3;
    }
    __syncthreads();
    if (tid < 512) {
        float sum = 0.f;
        #pragma unroll
        for (int w = 0; w < 16; ++w) sum += cpart[w][tid];
        sh_v[tid] = grcp(sum);
    }
    __syncthreads();

    // ---------------- 9 fused sweeps: row(v)->u, col(u)->v', one matrix read
    #pragma unroll 1
    for (int sw = 0; sw < 9; ++sw) {
        const float4 va = *(const float4*)&sh_v[wl * 8];
        const float4 vb = *(const float4*)&sh_v[wl * 8 + 4];
        float ce0=0,co0=0,ce1=0,co1=0,ce2=0,co2=0,ce3=0,co3=0;
        #pragma unroll 4
        for (int g = 0; g < 32; ++g) {
            const int i = (g << 4) + wv;
            uint4 wq = *(const uint4*)(wp + i * 256);
            float p = blo(wq.x)*va.x + bhi(wq.x)*va.y
                    + blo(wq.y)*va.z + bhi(wq.y)*va.w
                    + blo(wq.z)*vb.x + bhi(wq.z)*vb.y
                    + blo(wq.w)*vb.z + bhi(wq.w)*vb.w;
            p += __shfl_xor(p, 1);  p += __shfl_xor(p, 2);  p += __shfl_xor(p, 4);
            p += __shfl_xor(p, 8);  p += __shfl_xor(p, 16); p += __shfl_xor(p, 32);
            const float u = grcp(p);                 // row i's u, all lanes
            ce0 += blo(wq.x)*u; co0 += bhi(wq.x)*u;
            ce1 += blo(wq.y)*u; co1 += bhi(wq.y)*u;
            ce2 += blo(wq.z)*u; co2 += bhi(wq.z)*u;
            ce3 += blo(wq.w)*u; co3 += bhi(wq.w)*u;
        }
        float* cw = &cpart[wv][wl * 8];
        cw[0]=ce0; cw[1]=co0; cw[2]=ce1; cw[3]=co1;
        cw[4]=ce2; cw[5]=co2; cw[6]=ce3; cw[7]=co3;
        __syncthreads();
        if (tid < 512) {
            float sum = 0.f;
            #pragma unroll
            for (int w = 0; w < 16; ++w) sum += cpart[w][tid];
            sh_v[tid] = grcp(sum);
        }
        __syncthreads();
    }

    // ---------------- final row-only pass: u from v10, store sh_u
    {
        const float4 va = *(const float4*)&sh_v[wl * 8];
        const float4 vb = *(const float4*)&sh_v[wl * 8 + 4];
        #pragma unroll 4
        for (int g = 0; g < 32; ++g) {
            const int i = (g << 4) + wv;
            uint4 wq = *(const uint4*)(wp + i * 256);
            float p = blo(wq.x)*va.x + bhi(wq.x)*va.y
                    + blo(wq.y)*va.z + bhi(wq.y)*va.w
                    + blo(wq.z)*vb.x + bhi(wq.z)*vb.y
                    + blo(wq.w)*vb.z + bhi(wq.w)*vb.w;
            p += __shfl_xor(p, 1);  p += __shfl_xor(p, 2);  p += __shfl_xor(p, 4);
            p += __shfl_xor(p, 8);  p += __shfl_xor(p, 16); p += __shfl_xor(p, 32);
            if (wl == 0) sh_u[i] = grcp(p);
        }
    }
    __syncthreads();   // sh_u visible; all sweep reads of W0 complete

    // ---------------- epilogue: out = a * u_i * v_j from W0
    // stage chunk 15's W0 rows (480..511, 32KB) before any overwrite
    uu* stg = (uu*)cpart;
    {
        uint4* d4 = (uint4*)stg;
        const uint4* s4 = (const uint4*)(W0 + 480 * 256);
        d4[tid]        = s4[tid];
        d4[tid + 1024] = s4[tid + 1024];
    }
    __syncthreads();
    {
        const int p  = tid & 127;   // float4 index within a row
        const int rs = tid >> 7;    // 0..7 (wave-uniform pairwise)
        const float4 vv = make_float4(sh_v[4*p], sh_v[4*p+1], sh_v[4*p+2], sh_v[4*p+3]);
        #pragma unroll 1
        for (int m = 0; m < 16; ++m) {
            if (m >= 8) __syncthreads();   // chunks < m done before their W0 rows die
            #pragma unroll
            for (int it = 0; it < 4; ++it) {
                const int i = (m << 5) + (it << 3) + rs;
                const uint2 tw = (m == 15)
                    ? *(const uint2*)(stg + (i - 480) * 256 + 2 * p)
                    : *(const uint2*)(W0 + i * 256 + 2 * p);
                const float uk = sh_u[i];    // wave-uniform broadcast
                float4 o;
                o.x = blo(tw.x) * uk * vv.x;
                o.y = bhi(tw.x) * uk * vv.y;
                o.z = blo(tw.y) * uk * vv.z;
                o.w = bhi(tw.y) * uk * vv.w;
                ob4[i * 128 + p] = o;        // coalesced 16B/lane
            }
        }
    }
}

extern "C" void kernel_launch(void* const* d_in, const int* in_sizes, int n_in,
                              void* d_out, int out_size, void* d_ws, size_t ws_size,
                              hipStream_t stream) {
    const float* s     = (const float*)d_in[0];
    const int*   nrows = (const int*)d_in[1];
    const int*   ncols = (const int*)d_in[2];
    float*       out   = (float*)d_out;
    const int B = in_sizes[1];   // 256 batches, one 1024-thread block each
    sinkhorn_kernel<<<dim3(B), dim3(1024), 0, stream>>>(s, nrows, ncols, out);
}